// Round 1
// baseline (191.498 us; speedup 1.0000x reference)
//
#include <hip/hip_runtime.h>

// Problem constants: B=2, S=2048, D=1024, H=16, HD=64
#define B_  2
#define S_  2048
#define D_  1024
#define H_  16
#define HD_ 64
#define TD_ 3072   // 3*D

typedef __bf16 bf16x8 __attribute__((ext_vector_type(8)));
typedef float  f32x4  __attribute__((ext_vector_type(4)));

#define AS1 __attribute__((address_space(1)))
#define AS3 __attribute__((address_space(3)))

__device__ __forceinline__ unsigned short f2bf(float f) {
  return __builtin_bit_cast(unsigned short, (__bf16)f);
}

__device__ __forceinline__ void gload16(const void* g, void* l) {
  __builtin_amdgcn_global_load_lds((const AS1 void*)g, (AS3 void*)l, 16, 0, 0);
}

// ---------------- prep: x fp32 -> bf16 ----------------
__global__ __launch_bounds__(256) void k_convert_x(const float* __restrict__ x,
                                                   unsigned short* __restrict__ xb) {
  const int i = (blockIdx.x * 256 + threadIdx.x) * 4;
  float4 v = *(const float4*)(x + i);
  ushort4 o;
  o.x = f2bf(v.x); o.y = f2bf(v.y); o.z = f2bf(v.z); o.w = f2bf(v.w);
  *(ushort4*)(xb + i) = o;
}

// ---------------- prep: W [R][C] fp32 -> Wt [C][R] bf16 ----------------
__global__ __launch_bounds__(256) void k_transpose_w(const float* __restrict__ w,
                                                     unsigned short* __restrict__ wt,
                                                     int R, int C) {
  __shared__ __align__(16) unsigned short tile[64][72];
  const int t = threadIdx.x;
  const int c0 = blockIdx.x * 64, r0 = blockIdx.y * 64;
  const int rr = t >> 2, cc = (t & 3) * 16;
  const float* src = w + (size_t)(r0 + rr) * C + c0 + cc;
#pragma unroll
  for (int j = 0; j < 16; j += 4) {
    float4 v = *(const float4*)(src + j);
    tile[rr][cc + j + 0] = f2bf(v.x);
    tile[rr][cc + j + 1] = f2bf(v.y);
    tile[rr][cc + j + 2] = f2bf(v.z);
    tile[rr][cc + j + 3] = f2bf(v.w);
  }
  __syncthreads();
  unsigned short* dst = wt + (size_t)(c0 + rr) * R + r0 + cc;
#pragma unroll
  for (int j = 0; j < 16; j += 2) {
    unsigned int pk = (unsigned int)tile[cc + j][rr] |
                      ((unsigned int)tile[cc + j + 1][rr] << 16);
    *(unsigned int*)(dst + j) = pk;
  }
}

// ---------------- prep: V from qkv -> vt [b*h][hd][s] bf16 ----------------
__global__ __launch_bounds__(256) void k_transpose_v(const unsigned short* __restrict__ qkv,
                                                     unsigned short* __restrict__ vt) {
  __shared__ __align__(16) unsigned short tile[64][72];
  const int t = threadIdx.x;
  const int s0 = blockIdx.x * 64;
  const int bh = blockIdx.y;              // b*16 + h
  const int b = bh >> 4, h = bh & 15;
  const int rr = t >> 2, cc = (t & 3) * 16;
  const unsigned short* src =
      qkv + (size_t)(b * S_ + s0 + rr) * TD_ + 2 * D_ + h * HD_ + cc;
#pragma unroll
  for (int j = 0; j < 16; j += 8) {
    uint4 v = *(const uint4*)(src + j);
    *(uint4*)&tile[rr][cc + j] = v;
  }
  __syncthreads();
  unsigned short* dst = vt + (size_t)(bh * HD_ + rr) * S_ + s0 + cc;
#pragma unroll
  for (int j = 0; j < 16; j += 2) {
    unsigned int pk = (unsigned int)tile[cc + j][rr] |
                      ((unsigned int)tile[cc + j + 1][rr] << 16);
    *(unsigned int*)(dst + j) = pk;
  }
}

// ---------------- GEMM: C[M][N] = A[M][K] * Bt[N][K]^T ----------------
// 128x128 tile, BK=64, 4 waves (2x2), each wave 64x64 out.
// LDS rows are 128B; XOR swizzle slot^=(row&7) on read, inverse-swizzled
// global source feeding linear global_load_lds destinations.
template <int BF16_OUT>
__global__ __launch_bounds__(256) void k_gemm_bt(const unsigned short* __restrict__ A,
                                                 const unsigned short* __restrict__ Bt,
                                                 void* __restrict__ Cv,
                                                 int Ndim, int K) {
  __shared__ __align__(16) unsigned short ldsA[128 * 64];
  __shared__ __align__(16) unsigned short ldsB[128 * 64];
  const int t = threadIdx.x;
  const int lane = t & 63;
  const int wid = t >> 6;
  const int wr = wid >> 1, wc = wid & 1;
  const int bm = blockIdx.y * 128, bn = blockIdx.x * 128;
  const int r = lane & 15, g = lane >> 4;

  f32x4 acc[4][4] = {};

  for (int kt = 0; kt < K; kt += 64) {
#pragma unroll
    for (int c = 0; c < 4; ++c) {
      const int idx = c * 256 + t;
      const int row = idx >> 3;
      const int col = ((idx & 7) ^ (row & 7)) * 8;   // inverse-swizzled source
      gload16(A + (size_t)(bm + row) * K + kt + col, ldsA + idx * 8);
      gload16(Bt + (size_t)(bn + row) * K + kt + col, ldsB + idx * 8);
    }
    asm volatile("s_waitcnt vmcnt(0)" ::: "memory");
    __syncthreads();
#pragma unroll
    for (int ks = 0; ks < 2; ++ks) {
      bf16x8 af[4], bfr[4];
#pragma unroll
      for (int m = 0; m < 4; ++m) {
        const int row = wr * 64 + m * 16 + r;
        const int slot = (ks * 4 + g) ^ (row & 7);
        af[m] = *(const bf16x8*)(ldsA + row * 64 + slot * 8);
      }
#pragma unroll
      for (int n = 0; n < 4; ++n) {
        const int row = wc * 64 + n * 16 + r;
        const int slot = (ks * 4 + g) ^ (row & 7);
        bfr[n] = *(const bf16x8*)(ldsB + row * 64 + slot * 8);
      }
#pragma unroll
      for (int m = 0; m < 4; ++m)
#pragma unroll
        for (int n = 0; n < 4; ++n)
          acc[m][n] = __builtin_amdgcn_mfma_f32_16x16x32_bf16(af[m], bfr[n],
                                                              acc[m][n], 0, 0, 0);
    }
    __syncthreads();
  }

  const int row0 = bm + wr * 64 + g * 4;   // + m*16 + i
  const int col0 = bn + wc * 64 + r;       // + n*16
  if constexpr (BF16_OUT) {
    unsigned short* C = (unsigned short*)Cv;
#pragma unroll
    for (int m = 0; m < 4; ++m)
#pragma unroll
      for (int n = 0; n < 4; ++n)
#pragma unroll
        for (int i = 0; i < 4; ++i)
          C[(size_t)(row0 + m * 16 + i) * Ndim + col0 + n * 16] = f2bf(acc[m][n][i]);
  } else {
    float* C = (float*)Cv;
#pragma unroll
    for (int m = 0; m < 4; ++m)
#pragma unroll
      for (int n = 0; n < 4; ++n)
#pragma unroll
        for (int i = 0; i < 4; ++i)
          C[(size_t)(row0 + m * 16 + i) * Ndim + col0 + n * 16] = acc[m][n][i];
  }
}

// ---------------- fused causal attention ----------------
// Block = (b, h, 64 q-rows); 4 waves, wave w owns q-rows [q0, q0+16).
// Q in registers; K tile [kv64][hd64], Vt tile [hd64][kv64] in swizzled LDS;
// online softmax; P through wave-private swizzled LDS to feed PV MFMA.
__global__ __launch_bounds__(256) void k_attn(const unsigned short* __restrict__ qkv,
                                              const unsigned short* __restrict__ vt,
                                              unsigned short* __restrict__ y) {
  __shared__ __align__(16) unsigned short ldsK[64 * 64];
  __shared__ __align__(16) unsigned short ldsV[64 * 64];
  __shared__ __align__(16) unsigned short ldsP[4][16 * 64];
  const int t = threadIdx.x;
  const int lane = t & 63, w = t >> 6;
  const int r = lane & 15, g = lane >> 4;
  const int qb = blockIdx.x & 31;
  const int bh = blockIdx.x >> 5;
  const int h = bh & 15, b = bh >> 4;
  const int q0 = qb * 64 + w * 16;

  bf16x8 qf[2];
  {
    const unsigned short* qp =
        qkv + (size_t)(b * S_ + q0 + r) * TD_ + h * HD_ + g * 8;
    qf[0] = *(const bf16x8*)qp;
    qf[1] = *(const bf16x8*)(qp + 32);
  }

  float mrow[4], lrow[4];
  f32x4 yacc[4] = {};
#pragma unroll
  for (int i = 0; i < 4; ++i) { mrow[i] = -1e30f; lrow[i] = 0.f; }

  const int nkv = qb + 1;
  for (int kvt = 0; kvt < nkv; ++kvt) {
    const int kv0 = kvt * 64;
#pragma unroll
    for (int c = 0; c < 2; ++c) {
      const int idx = c * 256 + t;
      const int row = idx >> 3;
      const int col = ((idx & 7) ^ (row & 7)) * 8;
      gload16(qkv + (size_t)(b * S_ + kv0 + row) * TD_ + D_ + h * HD_ + col,
              ldsK + idx * 8);
      gload16(vt + (size_t)(bh * HD_ + row) * S_ + kv0 + col, ldsV + idx * 8);
    }
    asm volatile("s_waitcnt vmcnt(0)" ::: "memory");
    __syncthreads();

    // S = Q K^T  (per wave: 16 q-rows x 64 kv)
    f32x4 sacc[4] = {};
#pragma unroll
    for (int ks = 0; ks < 2; ++ks) {
#pragma unroll
      for (int n = 0; n < 4; ++n) {
        const int row = n * 16 + r;
        const int slot = (ks * 4 + g) ^ (row & 7);
        bf16x8 kf = *(const bf16x8*)(ldsK + row * 64 + slot * 8);
        sacc[n] = __builtin_amdgcn_mfma_f32_16x16x32_bf16(qf[ks], kf, sacc[n], 0, 0, 0);
      }
    }

    // scale + causal mask + row max (rows live across 16 lanes of same g)
    float pmax[4];
#pragma unroll
    for (int i = 0; i < 4; ++i) {
      const int qg = q0 + g * 4 + i;
      float v = -1e30f;
#pragma unroll
      for (int n = 0; n < 4; ++n) {
        float s = sacc[n][i] * 0.125f;
        const int kvg = kv0 + n * 16 + r;
        s = (kvg <= qg) ? s : -1e30f;
        sacc[n][i] = s;
        v = fmaxf(v, s);
      }
      pmax[i] = v;
    }
#pragma unroll
    for (int msk = 1; msk < 16; msk <<= 1)
#pragma unroll
      for (int i = 0; i < 4; ++i)
        pmax[i] = fmaxf(pmax[i], __shfl_xor(pmax[i], msk, 64));

    float corr[4], psum[4];
#pragma unroll
    for (int i = 0; i < 4; ++i) {
      const float mnew = fmaxf(mrow[i], pmax[i]);
      corr[i] = __expf(mrow[i] - mnew);
      mrow[i] = mnew;
      psum[i] = 0.f;
    }
#pragma unroll
    for (int n = 0; n < 4; ++n)
#pragma unroll
      for (int i = 0; i < 4; ++i) {
        const float p = __expf(sacc[n][i] - mrow[i]);
        sacc[n][i] = p;
        psum[i] += p;
      }
#pragma unroll
    for (int msk = 1; msk < 16; msk <<= 1)
#pragma unroll
      for (int i = 0; i < 4; ++i)
        psum[i] += __shfl_xor(psum[i], msk, 64);
#pragma unroll
    for (int i = 0; i < 4; ++i) lrow[i] = lrow[i] * corr[i] + psum[i];
#pragma unroll
    for (int n = 0; n < 4; ++n)
#pragma unroll
      for (int i = 0; i < 4; ++i) yacc[n][i] *= corr[i];

    // P -> wave-private LDS (bf16, swizzled rows of 128B)
    unsigned short* pl = (unsigned short*)ldsP[w];
#pragma unroll
    for (int n = 0; n < 4; ++n)
#pragma unroll
      for (int i = 0; i < 4; ++i) {
        const int prow = g * 4 + i;
        int byteoff = prow * 128 + (n * 16 + r) * 2;
        byteoff ^= (prow & 7) << 4;
        *(unsigned short*)((char*)pl + byteoff) = f2bf(sacc[n][i]);
      }
    asm volatile("s_waitcnt lgkmcnt(0)" ::: "memory");
    __builtin_amdgcn_sched_barrier(0);

    // yacc += P @ V  (A = P[16][64], B = V[64][hd16-tile] via Vt rows)
#pragma unroll
    for (int ks = 0; ks < 2; ++ks) {
      const int pslot = (ks * 4 + g) ^ (r & 7);
      bf16x8 pf = *(const bf16x8*)(pl + r * 64 + pslot * 8);
#pragma unroll
      for (int n = 0; n < 4; ++n) {
        const int vrow = n * 16 + r;
        const int vslot = (ks * 4 + g) ^ (vrow & 7);
        bf16x8 vf = *(const bf16x8*)(ldsV + vrow * 64 + vslot * 8);
        yacc[n] = __builtin_amdgcn_mfma_f32_16x16x32_bf16(pf, vf, yacc[n], 0, 0, 0);
      }
    }
    __syncthreads();
  }

  // epilogue: y = yacc / l, store bf16 [b, s, h*64+hd]
#pragma unroll
  for (int i = 0; i < 4; ++i) {
    const float inv = 1.f / lrow[i];
    const int qg = q0 + g * 4 + i;
    unsigned short* yp = y + (size_t)(b * S_ + qg) * D_ + h * HD_ + r;
#pragma unroll
    for (int n = 0; n < 4; ++n) yp[n * 16] = f2bf(yacc[n][i] * inv);
  }
}

// ---------------- launch ----------------
extern "C" void kernel_launch(void* const* d_in, const int* in_sizes, int n_in,
                              void* d_out, int out_size, void* d_ws, size_t ws_size,
                              hipStream_t stream) {
  const float* x  = (const float*)d_in[0];   // [2,2048,1024]
  const float* wa = (const float*)d_in[1];   // [1024,3072]
  const float* wp = (const float*)d_in[2];   // [1024,1024]
  float* out = (float*)d_out;                // [2,2048,1024] fp32

  char* ws = (char*)d_ws;
  // ws layout (bytes), all 256B-aligned; total = 56 MiB
  unsigned short* xb  = (unsigned short*)(ws + 0);          //  8 MiB: x bf16 [4096][1024]
  unsigned short* waT = (unsigned short*)(ws + 8388608);    //  6 MiB: w_attn^T [3072][1024]
  unsigned short* wpT = (unsigned short*)(ws + 14680064);   //  2 MiB: w_proj^T [1024][1024]
  unsigned short* qkv = (unsigned short*)(ws + 16777216);   // 24 MiB: [4096][3072]
  unsigned short* vtb = (unsigned short*)(ws + 41943040);   //  8 MiB: [32][64][2048]
  unsigned short* yb  = (unsigned short*)(ws + 50331648);   //  8 MiB: [4096][1024]

  k_convert_x<<<4096, 256, 0, stream>>>(x, xb);
  k_transpose_w<<<dim3(48, 16), 256, 0, stream>>>(wa, waT, D_, TD_);
  k_transpose_w<<<dim3(16, 16), 256, 0, stream>>>(wp, wpT, D_, D_);
  k_gemm_bt<1><<<dim3(24, 32), 256, 0, stream>>>(xb, waT, qkv, TD_, D_);
  k_transpose_v<<<dim3(32, 32), 256, 0, stream>>>(qkv, vtb);
  k_attn<<<1024, 256, 0, stream>>>(qkv, vtb, yb);
  k_gemm_bt<0><<<dim3(8, 32), 256, 0, stream>>>(yb, wpT, out, D_, D_);
}

// Round 2
// 150.033 us; speedup vs baseline: 1.2764x; 1.2764x over previous
//
#include <hip/hip_runtime.h>

// Problem constants: B=2, S=2048, D=1024, H=16, HD=64
#define B_  2
#define S_  2048
#define D_  1024
#define H_  16
#define HD_ 64
#define TD_ 3072   // 3*D

typedef __bf16 bf16x8 __attribute__((ext_vector_type(8)));
typedef float  f32x4  __attribute__((ext_vector_type(4)));

#define AS1 __attribute__((address_space(1)))
#define AS3 __attribute__((address_space(3)))

__device__ __forceinline__ unsigned short f2bf(float f) {
  return __builtin_bit_cast(unsigned short, (__bf16)f);
}

__device__ __forceinline__ void gload16(const void* g, void* l) {
  __builtin_amdgcn_global_load_lds((const AS1 void*)g, (AS3 void*)l, 16, 0, 0);
}

// ---------------- prep: x fp32 -> bf16 ----------------
__global__ __launch_bounds__(256) void k_convert_x(const float* __restrict__ x,
                                                   unsigned short* __restrict__ xb) {
  const int i = (blockIdx.x * 256 + threadIdx.x) * 4;
  float4 v = *(const float4*)(x + i);
  ushort4 o;
  o.x = f2bf(v.x); o.y = f2bf(v.y); o.z = f2bf(v.z); o.w = f2bf(v.w);
  *(ushort4*)(xb + i) = o;
}

// ---------------- prep: W [R][C] fp32 -> Wt [C][R] bf16 ----------------
__global__ __launch_bounds__(256) void k_transpose_w(const float* __restrict__ w,
                                                     unsigned short* __restrict__ wt,
                                                     int R, int C) {
  __shared__ __align__(16) unsigned short tile[64][72];
  const int t = threadIdx.x;
  const int c0 = blockIdx.x * 64, r0 = blockIdx.y * 64;
  const int rr = t >> 2, cc = (t & 3) * 16;
  const float* src = w + (size_t)(r0 + rr) * C + c0 + cc;
#pragma unroll
  for (int j = 0; j < 16; j += 4) {
    float4 v = *(const float4*)(src + j);
    tile[rr][cc + j + 0] = f2bf(v.x);
    tile[rr][cc + j + 1] = f2bf(v.y);
    tile[rr][cc + j + 2] = f2bf(v.z);
    tile[rr][cc + j + 3] = f2bf(v.w);
  }
  __syncthreads();
  unsigned short* dst = wt + (size_t)(c0 + rr) * R + r0 + cc;
#pragma unroll
  for (int j = 0; j < 16; j += 2) {
    unsigned int pk = (unsigned int)tile[cc + j][rr] |
                      ((unsigned int)tile[cc + j + 1][rr] << 16);
    *(unsigned int*)(dst + j) = pk;
  }
}

// ---------------- prep: V from qkv -> vt [b*h][hd][s] bf16 ----------------
__global__ __launch_bounds__(256) void k_transpose_v(const unsigned short* __restrict__ qkv,
                                                     unsigned short* __restrict__ vt) {
  __shared__ __align__(16) unsigned short tile[64][72];
  const int t = threadIdx.x;
  const int s0 = blockIdx.x * 64;
  const int bh = blockIdx.y;              // b*16 + h
  const int b = bh >> 4, h = bh & 15;
  const int rr = t >> 2, cc = (t & 3) * 16;
  const unsigned short* src =
      qkv + (size_t)(b * S_ + s0 + rr) * TD_ + 2 * D_ + h * HD_ + cc;
#pragma unroll
  for (int j = 0; j < 16; j += 8) {
    uint4 v = *(const uint4*)(src + j);
    *(uint4*)&tile[rr][cc + j] = v;
  }
  __syncthreads();
  unsigned short* dst = vt + (size_t)(bh * HD_ + rr) * S_ + s0 + cc;
#pragma unroll
  for (int j = 0; j < 16; j += 2) {
    unsigned int pk = (unsigned int)tile[cc + j][rr] |
                      ((unsigned int)tile[cc + j + 1][rr] << 16);
    *(unsigned int*)(dst + j) = pk;
  }
}

// ---------------- GEMM: C[M][N] = A[M][K] * Bt[N][K]^T ----------------
// 128x128 tile, BK=64, 4 waves (2x2), each wave 64x64 out.
template <int BF16_OUT>
__global__ __launch_bounds__(256) void k_gemm_bt(const unsigned short* __restrict__ A,
                                                 const unsigned short* __restrict__ Bt,
                                                 void* __restrict__ Cv,
                                                 int Ndim, int K) {
  __shared__ __align__(16) unsigned short ldsA[128 * 64];
  __shared__ __align__(16) unsigned short ldsB[128 * 64];
  const int t = threadIdx.x;
  const int lane = t & 63;
  const int wid = t >> 6;
  const int wr = wid >> 1, wc = wid & 1;
  const int bm = blockIdx.y * 128, bn = blockIdx.x * 128;
  const int r = lane & 15, g = lane >> 4;

  f32x4 acc[4][4] = {};

  for (int kt = 0; kt < K; kt += 64) {
#pragma unroll
    for (int c = 0; c < 4; ++c) {
      const int idx = c * 256 + t;
      const int row = idx >> 3;
      const int col = ((idx & 7) ^ (row & 7)) * 8;   // inverse-swizzled source
      gload16(A + (size_t)(bm + row) * K + kt + col, ldsA + idx * 8);
      gload16(Bt + (size_t)(bn + row) * K + kt + col, ldsB + idx * 8);
    }
    asm volatile("s_waitcnt vmcnt(0)" ::: "memory");
    __syncthreads();
#pragma unroll
    for (int ks = 0; ks < 2; ++ks) {
      bf16x8 af[4], bfr[4];
#pragma unroll
      for (int m = 0; m < 4; ++m) {
        const int row = wr * 64 + m * 16 + r;
        const int slot = (ks * 4 + g) ^ (row & 7);
        af[m] = *(const bf16x8*)(ldsA + row * 64 + slot * 8);
      }
#pragma unroll
      for (int n = 0; n < 4; ++n) {
        const int row = wc * 64 + n * 16 + r;
        const int slot = (ks * 4 + g) ^ (row & 7);
        bfr[n] = *(const bf16x8*)(ldsB + row * 64 + slot * 8);
      }
#pragma unroll
      for (int m = 0; m < 4; ++m)
#pragma unroll
        for (int n = 0; n < 4; ++n)
          acc[m][n] = __builtin_amdgcn_mfma_f32_16x16x32_bf16(af[m], bfr[n],
                                                              acc[m][n], 0, 0, 0);
    }
    __syncthreads();
  }

  const int row0 = bm + wr * 64 + g * 4;   // + m*16 + i
  const int col0 = bn + wc * 64 + r;       // + n*16
  if constexpr (BF16_OUT) {
    unsigned short* C = (unsigned short*)Cv;
#pragma unroll
    for (int m = 0; m < 4; ++m)
#pragma unroll
      for (int n = 0; n < 4; ++n)
#pragma unroll
        for (int i = 0; i < 4; ++i)
          C[(size_t)(row0 + m * 16 + i) * Ndim + col0 + n * 16] = f2bf(acc[m][n][i]);
  } else {
    float* C = (float*)Cv;
#pragma unroll
    for (int m = 0; m < 4; ++m)
#pragma unroll
      for (int n = 0; n < 4; ++n)
#pragma unroll
        for (int i = 0; i < 4; ++i)
          C[(size_t)(row0 + m * 16 + i) * Ndim + col0 + n * 16] = acc[m][n][i];
  }
}

// ---------------- fused causal attention ----------------
// Block = (b, h, 64 q-rows); 4 waves, wave w owns q-rows [q0, q0+16).
// qslot-major block mapping: qb = 31 - (blockIdx.x>>5), bh = blockIdx.x&31.
//   -> each CU hosts blocks from different work quartiles (balanced), and
//      all 32 blocks of one bh land on XCD bh%8 (K/V L2-resident).
// Double-buffered K/V staging: issue tile t+1 while computing tile t.
__global__ __launch_bounds__(256) void k_attn(const unsigned short* __restrict__ qkv,
                                              const unsigned short* __restrict__ vt,
                                              unsigned short* __restrict__ y) {
  __shared__ __align__(16) unsigned short ldsK[2][64 * 64];
  __shared__ __align__(16) unsigned short ldsV[2][64 * 64];
  __shared__ __align__(16) unsigned short ldsP[4][16 * 64];
  const int t = threadIdx.x;
  const int lane = t & 63, w = t >> 6;
  const int r = lane & 15, g = lane >> 4;
  const int bh = blockIdx.x & 31;
  const int qb = 31 - (blockIdx.x >> 5);
  const int h = bh & 15, b = bh >> 4;
  const int q0 = qb * 64 + w * 16;

  bf16x8 qf[2];
  {
    const unsigned short* qp =
        qkv + (size_t)(b * S_ + q0 + r) * TD_ + h * HD_ + g * 8;
    qf[0] = *(const bf16x8*)qp;
    qf[1] = *(const bf16x8*)(qp + 32);
  }

  float mrow[4], lrow[4];
  f32x4 yacc[4] = {};
#pragma unroll
  for (int i = 0; i < 4; ++i) { mrow[i] = -1e30f; lrow[i] = 0.f; }

  // stage one 64-kv tile (K + Vt) into buffer `buf`
  auto stage = [&](int buf, int kv0) {
#pragma unroll
    for (int c = 0; c < 2; ++c) {
      const int idx = c * 256 + t;
      const int row = idx >> 3;
      const int col = ((idx & 7) ^ (row & 7)) * 8;
      gload16(qkv + (size_t)(b * S_ + kv0 + row) * TD_ + D_ + h * HD_ + col,
              &ldsK[buf][idx * 8]);
      gload16(vt + (size_t)(bh * HD_ + row) * S_ + kv0 + col,
              &ldsV[buf][idx * 8]);
    }
  };

  const int nkv = qb + 1;
  stage(0, 0);
  asm volatile("s_waitcnt vmcnt(0)" ::: "memory");
  __syncthreads();

  for (int kvt = 0; kvt < nkv; ++kvt) {
    const int cur = kvt & 1;
    const int kv0 = kvt * 64;
    if (kvt + 1 < nkv) stage(cur ^ 1, (kvt + 1) * 64);

    // S = Q K^T  (per wave: 16 q-rows x 64 kv)
    f32x4 sacc[4] = {};
    __builtin_amdgcn_s_setprio(1);
#pragma unroll
    for (int ks = 0; ks < 2; ++ks) {
#pragma unroll
      for (int n = 0; n < 4; ++n) {
        const int row = n * 16 + r;
        const int slot = (ks * 4 + g) ^ (row & 7);
        bf16x8 kf = *(const bf16x8*)(&ldsK[cur][row * 64 + slot * 8]);
        sacc[n] = __builtin_amdgcn_mfma_f32_16x16x32_bf16(qf[ks], kf, sacc[n], 0, 0, 0);
      }
    }
    __builtin_amdgcn_s_setprio(0);

    // scale + causal mask + row max (rows live across 16 lanes of same g)
    float pmax[4];
#pragma unroll
    for (int i = 0; i < 4; ++i) {
      const int qg = q0 + g * 4 + i;
      float v = -1e30f;
#pragma unroll
      for (int n = 0; n < 4; ++n) {
        float s = sacc[n][i] * 0.125f;
        const int kvg = kv0 + n * 16 + r;
        s = (kvg <= qg) ? s : -1e30f;
        sacc[n][i] = s;
        v = fmaxf(v, s);
      }
      pmax[i] = v;
    }
#pragma unroll
    for (int msk = 1; msk < 16; msk <<= 1)
#pragma unroll
      for (int i = 0; i < 4; ++i)
        pmax[i] = fmaxf(pmax[i], __shfl_xor(pmax[i], msk, 64));

    float corr[4], psum[4];
#pragma unroll
    for (int i = 0; i < 4; ++i) {
      const float mnew = fmaxf(mrow[i], pmax[i]);
      corr[i] = __expf(mrow[i] - mnew);
      mrow[i] = mnew;
      psum[i] = 0.f;
    }
#pragma unroll
    for (int n = 0; n < 4; ++n)
#pragma unroll
      for (int i = 0; i < 4; ++i) {
        const float p = __expf(sacc[n][i] - mrow[i]);
        sacc[n][i] = p;
        psum[i] += p;
      }
#pragma unroll
    for (int msk = 1; msk < 16; msk <<= 1)
#pragma unroll
      for (int i = 0; i < 4; ++i)
        psum[i] += __shfl_xor(psum[i], msk, 64);
#pragma unroll
    for (int i = 0; i < 4; ++i) lrow[i] = lrow[i] * corr[i] + psum[i];
#pragma unroll
    for (int n = 0; n < 4; ++n)
#pragma unroll
      for (int i = 0; i < 4; ++i) yacc[n][i] *= corr[i];

    // P -> wave-private LDS (bf16, swizzled rows of 128B)
    unsigned short* pl = (unsigned short*)ldsP[w];
#pragma unroll
    for (int n = 0; n < 4; ++n)
#pragma unroll
      for (int i = 0; i < 4; ++i) {
        const int prow = g * 4 + i;
        int byteoff = prow * 128 + (n * 16 + r) * 2;
        byteoff ^= (prow & 7) << 4;
        *(unsigned short*)((char*)pl + byteoff) = f2bf(sacc[n][i]);
      }
    asm volatile("s_waitcnt lgkmcnt(0)" ::: "memory");
    __builtin_amdgcn_sched_barrier(0);

    // yacc += P @ V  (A = P[16][64], B = V[64][hd16-tile] via Vt rows)
    __builtin_amdgcn_s_setprio(1);
#pragma unroll
    for (int ks = 0; ks < 2; ++ks) {
      const int pslot = (ks * 4 + g) ^ (r & 7);
      bf16x8 pf = *(const bf16x8*)(pl + r * 64 + pslot * 8);
#pragma unroll
      for (int n = 0; n < 4; ++n) {
        const int vrow = n * 16 + r;
        const int vslot = (ks * 4 + g) ^ (vrow & 7);
        bf16x8 vf = *(const bf16x8*)(&ldsV[cur][vrow * 64 + vslot * 8]);
        yacc[n] = __builtin_amdgcn_mfma_f32_16x16x32_bf16(pf, vf, yacc[n], 0, 0, 0);
      }
    }
    __builtin_amdgcn_s_setprio(0);

    // wait for the next tile's staging, then flip buffers
    asm volatile("s_waitcnt vmcnt(0)" ::: "memory");
    __syncthreads();
  }

  // epilogue: y = yacc / l, store bf16 [b, s, h*64+hd]
#pragma unroll
  for (int i = 0; i < 4; ++i) {
    const float inv = 1.f / lrow[i];
    const int qg = q0 + g * 4 + i;
    unsigned short* yp = y + (size_t)(b * S_ + qg) * D_ + h * HD_ + r;
#pragma unroll
    for (int n = 0; n < 4; ++n) yp[n * 16] = f2bf(yacc[n][i] * inv);
  }
}

// ---------------- launch ----------------
extern "C" void kernel_launch(void* const* d_in, const int* in_sizes, int n_in,
                              void* d_out, int out_size, void* d_ws, size_t ws_size,
                              hipStream_t stream) {
  const float* x  = (const float*)d_in[0];   // [2,2048,1024]
  const float* wa = (const float*)d_in[1];   // [1024,3072]
  const float* wp = (const float*)d_in[2];   // [1024,1024]
  float* out = (float*)d_out;                // [2,2048,1024] fp32

  char* ws = (char*)d_ws;
  // ws layout (bytes), all 256B-aligned; total = 56 MiB
  unsigned short* xb  = (unsigned short*)(ws + 0);          //  8 MiB: x bf16 [4096][1024]
  unsigned short* waT = (unsigned short*)(ws + 8388608);    //  6 MiB: w_attn^T [3072][1024]
  unsigned short* wpT = (unsigned short*)(ws + 14680064);   //  2 MiB: w_proj^T [1024][1024]
  unsigned short* qkv = (unsigned short*)(ws + 16777216);   // 24 MiB: [4096][3072]
  unsigned short* vtb = (unsigned short*)(ws + 41943040);   //  8 MiB: [32][64][2048]
  unsigned short* yb  = (unsigned short*)(ws + 50331648);   //  8 MiB: [4096][1024]

  k_convert_x<<<4096, 256, 0, stream>>>(x, xb);
  k_transpose_w<<<dim3(48, 16), 256, 0, stream>>>(wa, waT, D_, TD_);
  k_transpose_w<<<dim3(16, 16), 256, 0, stream>>>(wp, wpT, D_, D_);
  k_gemm_bt<1><<<dim3(24, 32), 256, 0, stream>>>(xb, waT, qkv, TD_, D_);
  k_transpose_v<<<dim3(32, 32), 256, 0, stream>>>(qkv, vtb);
  k_attn<<<1024, 256, 0, stream>>>(qkv, vtb, yb);
  k_gemm_bt<0><<<dim3(8, 32), 256, 0, stream>>>(yb, wpT, out, D_, D_);
}

// Round 3
// 135.024 us; speedup vs baseline: 1.4183x; 1.1112x over previous
//
#include <hip/hip_runtime.h>

// Problem constants: B=2, S=2048, D=1024, H=16, HD=64
#define B_  2
#define S_  2048
#define D_  1024
#define H_  16
#define HD_ 64
#define TD_ 3072   // 3*D

typedef __bf16 bf16x8 __attribute__((ext_vector_type(8)));
typedef float  f32x4  __attribute__((ext_vector_type(4)));
typedef float  f32x16 __attribute__((ext_vector_type(16)));

#define AS1 __attribute__((address_space(1)))
#define AS3 __attribute__((address_space(3)))

__device__ __forceinline__ unsigned short f2bf(float f) {
  return __builtin_bit_cast(unsigned short, (__bf16)f);
}

__device__ __forceinline__ unsigned int pkbf(float lo, float hi) {
  unsigned int r;
  asm("v_cvt_pk_bf16_f32 %0, %1, %2" : "=v"(r) : "v"(lo), "v"(hi));
  return r;
}

// v_permlane32_swap_b32: a[32+i] <-> b[i]  (i in 0..31)
__device__ __forceinline__ void plswap(unsigned int& a, unsigned int& b) {
  asm volatile("v_permlane32_swap_b32 %0, %1" : "+v"(a), "+v"(b));
}

__device__ __forceinline__ void gload16(const void* g, void* l) {
  __builtin_amdgcn_global_load_lds((const AS1 void*)g, (AS3 void*)l, 16, 0, 0);
}

// ---------------- prep: x fp32 -> bf16 ----------------
__global__ __launch_bounds__(256) void k_convert_x(const float* __restrict__ x,
                                                   unsigned short* __restrict__ xb) {
  const int i = (blockIdx.x * 256 + threadIdx.x) * 4;
  float4 v = *(const float4*)(x + i);
  ushort4 o;
  o.x = f2bf(v.x); o.y = f2bf(v.y); o.z = f2bf(v.z); o.w = f2bf(v.w);
  *(ushort4*)(xb + i) = o;
}

// ---------------- prep: W [R][C] fp32 -> Wt [C][R] bf16 ----------------
__global__ __launch_bounds__(256) void k_transpose_w(const float* __restrict__ w,
                                                     unsigned short* __restrict__ wt,
                                                     int R, int C) {
  __shared__ __align__(16) unsigned short tile[64][72];
  const int t = threadIdx.x;
  const int c0 = blockIdx.x * 64, r0 = blockIdx.y * 64;
  const int rr = t >> 2, cc = (t & 3) * 16;
  const float* src = w + (size_t)(r0 + rr) * C + c0 + cc;
#pragma unroll
  for (int j = 0; j < 16; j += 4) {
    float4 v = *(const float4*)(src + j);
    tile[rr][cc + j + 0] = f2bf(v.x);
    tile[rr][cc + j + 1] = f2bf(v.y);
    tile[rr][cc + j + 2] = f2bf(v.z);
    tile[rr][cc + j + 3] = f2bf(v.w);
  }
  __syncthreads();
  unsigned short* dst = wt + (size_t)(c0 + rr) * R + r0 + cc;
#pragma unroll
  for (int j = 0; j < 16; j += 2) {
    unsigned int pk = (unsigned int)tile[cc + j][rr] |
                      ((unsigned int)tile[cc + j + 1][rr] << 16);
    *(unsigned int*)(dst + j) = pk;
  }
}

// ---------------- prep: V from qkv -> vt [b*h][hd][s] bf16 ----------------
__global__ __launch_bounds__(256) void k_transpose_v(const unsigned short* __restrict__ qkv,
                                                     unsigned short* __restrict__ vt) {
  __shared__ __align__(16) unsigned short tile[64][72];
  const int t = threadIdx.x;
  const int s0 = blockIdx.x * 64;
  const int bh = blockIdx.y;              // b*16 + h
  const int b = bh >> 4, h = bh & 15;
  const int rr = t >> 2, cc = (t & 3) * 16;
  const unsigned short* src =
      qkv + (size_t)(b * S_ + s0 + rr) * TD_ + 2 * D_ + h * HD_ + cc;
#pragma unroll
  for (int j = 0; j < 16; j += 8) {
    uint4 v = *(const uint4*)(src + j);
    *(uint4*)&tile[rr][cc + j] = v;
  }
  __syncthreads();
  unsigned short* dst = vt + (size_t)(bh * HD_ + rr) * S_ + s0 + cc;
#pragma unroll
  for (int j = 0; j < 16; j += 2) {
    unsigned int pk = (unsigned int)tile[cc + j][rr] |
                      ((unsigned int)tile[cc + j + 1][rr] << 16);
    *(unsigned int*)(dst + j) = pk;
  }
}

// ---------------- GEMM: C[M][N] = A[M][K] * Bt[N][K]^T ----------------
// 128x128 tile, BK=64, 4 waves (2x2), each wave 64x64 out.
template <int BF16_OUT>
__global__ __launch_bounds__(256) void k_gemm_bt(const unsigned short* __restrict__ A,
                                                 const unsigned short* __restrict__ Bt,
                                                 void* __restrict__ Cv,
                                                 int Ndim, int K) {
  __shared__ __align__(16) unsigned short ldsA[128 * 64];
  __shared__ __align__(16) unsigned short ldsB[128 * 64];
  const int t = threadIdx.x;
  const int lane = t & 63;
  const int wid = t >> 6;
  const int wr = wid >> 1, wc = wid & 1;
  const int bm = blockIdx.y * 128, bn = blockIdx.x * 128;
  const int r = lane & 15, g = lane >> 4;

  f32x4 acc[4][4] = {};

  for (int kt = 0; kt < K; kt += 64) {
#pragma unroll
    for (int c = 0; c < 4; ++c) {
      const int idx = c * 256 + t;
      const int row = idx >> 3;
      const int col = ((idx & 7) ^ (row & 7)) * 8;   // inverse-swizzled source
      gload16(A + (size_t)(bm + row) * K + kt + col, ldsA + idx * 8);
      gload16(Bt + (size_t)(bn + row) * K + kt + col, ldsB + idx * 8);
    }
    asm volatile("s_waitcnt vmcnt(0)" ::: "memory");
    __syncthreads();
#pragma unroll
    for (int ks = 0; ks < 2; ++ks) {
      bf16x8 af[4], bfr[4];
#pragma unroll
      for (int m = 0; m < 4; ++m) {
        const int row = wr * 64 + m * 16 + r;
        const int slot = (ks * 4 + g) ^ (row & 7);
        af[m] = *(const bf16x8*)(ldsA + row * 64 + slot * 8);
      }
#pragma unroll
      for (int n = 0; n < 4; ++n) {
        const int row = wc * 64 + n * 16 + r;
        const int slot = (ks * 4 + g) ^ (row & 7);
        bfr[n] = *(const bf16x8*)(ldsB + row * 64 + slot * 8);
      }
#pragma unroll
      for (int m = 0; m < 4; ++m)
#pragma unroll
        for (int n = 0; n < 4; ++n)
          acc[m][n] = __builtin_amdgcn_mfma_f32_16x16x32_bf16(af[m], bfr[n],
                                                              acc[m][n], 0, 0, 0);
    }
    __syncthreads();
  }

  const int row0 = bm + wr * 64 + g * 4;   // + m*16 + i
  const int col0 = bn + wc * 64 + r;       // + n*16
  if constexpr (BF16_OUT) {
    unsigned short* C = (unsigned short*)Cv;
#pragma unroll
    for (int m = 0; m < 4; ++m)
#pragma unroll
      for (int n = 0; n < 4; ++n)
#pragma unroll
        for (int i = 0; i < 4; ++i)
          C[(size_t)(row0 + m * 16 + i) * Ndim + col0 + n * 16] = f2bf(acc[m][n][i]);
  } else {
    float* C = (float*)Cv;
#pragma unroll
    for (int m = 0; m < 4; ++m)
#pragma unroll
      for (int n = 0; n < 4; ++n)
#pragma unroll
        for (int i = 0; i < 4; ++i)
          C[(size_t)(row0 + m * 16 + i) * Ndim + col0 + n * 16] = acc[m][n][i];
  }
}

// ---------------- fused causal attention (swapped-operand, 32x32 MFMA) ----
// Block = (b, h, 128 q-rows); 4 waves, wave w owns q-rows [q0w, q0w+32).
// S^T = mfma(K, Q): q = lane&31 -> softmax stats lane-local.
// O^T = mfma(V^T, P^T): q = lane&31 -> rescale is a per-lane scalar mul.
// P^T built in-register via cvt_pk_bf16 + permlane32_swap (no LDS round-trip).
// qslot pairing (s<8 ? s : 23-s) balances co-resident blocks to 34 tiles.
__global__ __launch_bounds__(256) void k_attn(const unsigned short* __restrict__ qkv,
                                              const unsigned short* __restrict__ vt,
                                              unsigned short* __restrict__ y) {
  __shared__ __align__(16) unsigned short ldsK[2][64 * 64];
  __shared__ __align__(16) unsigned short ldsV[2][64 * 64];
  const int t = threadIdx.x;
  const int lane = t & 63, w = t >> 6;
  const int l31 = lane & 31, hi = lane >> 5;
  const int bh = blockIdx.x & 31;
  const int s = blockIdx.x >> 5;            // 0..15
  const int qslot = (s < 8) ? s : 23 - s;   // pair heavy+light on a CU
  const int h = bh & 15, b = bh >> 4;
  const int q0w = qslot * 128 + w * 32;
  const int qq = q0w + l31;                 // this lane's q row

  // Q fragments (B-operand of mfma(K,Q)): qf[c][j] = Q[qq][c*16 + hi*8 + j] / 8
  bf16x8 qf[4];
  {
    const unsigned short* qp = qkv + (size_t)(b * S_ + qq) * TD_ + h * HD_;
#pragma unroll
    for (int c = 0; c < 4; ++c) {
      bf16x8 raw = *(const bf16x8*)(qp + c * 16 + hi * 8);
      union { unsigned int u[4]; bf16x8 v; } pq;
#pragma unroll
      for (int j = 0; j < 4; ++j)
        pq.u[j] = pkbf((float)raw[2 * j] * 0.125f, (float)raw[2 * j + 1] * 0.125f);
      qf[c] = pq.v;
    }
  }

  float mrow = -1e30f, lrow = 0.f;
  f32x16 oacc[2] = {};

  auto stage = [&](int buf, int kv0) {
#pragma unroll
    for (int c = 0; c < 2; ++c) {
      const int idx = c * 256 + t;
      const int row = idx >> 3;
      const int col = ((idx & 7) ^ (row & 7)) * 8;   // inverse-swizzled source
      gload16(qkv + (size_t)(b * S_ + kv0 + row) * TD_ + D_ + h * HD_ + col,
              &ldsK[buf][idx * 8]);
      gload16(vt + (size_t)(bh * HD_ + row) * S_ + kv0 + col,
              &ldsV[buf][idx * 8]);
    }
  };

  const int nkv = qslot * 2 + 2;
  stage(0, 0);
  asm volatile("s_waitcnt vmcnt(0)" ::: "memory");
  __syncthreads();

  for (int kvt = 0; kvt < nkv; ++kvt) {
    const int cur = kvt & 1;
    const int kv0 = kvt * 64;
    if (kvt + 1 < nkv) stage(cur ^ 1, kv0 + 64);

    if (kv0 <= q0w + 31) {   // wave-uniform: skip fully-masked tiles
      // S^T[kv][q] = K Q^T ; two 32-kv tiles
      f32x16 sacc[2] = {};
      __builtin_amdgcn_s_setprio(1);
#pragma unroll
      for (int T = 0; T < 2; ++T) {
        const int kvl = T * 32 + l31;
#pragma unroll
        for (int c = 0; c < 4; ++c) {
          const int slot = (2 * c + hi) ^ (kvl & 7);
          bf16x8 kf = *(const bf16x8*)(&ldsK[cur][kvl * 64 + slot * 8]);
          sacc[T] = __builtin_amdgcn_mfma_f32_32x32x16_bf16(kf, qf[c], sacc[T], 0, 0, 0);
        }
      }
      __builtin_amdgcn_s_setprio(0);

      // causal mask + lane-local max (q = l31 fixed per lane)
      float pmax = mrow;
      if (kv0 + 63 > q0w) {
#pragma unroll
        for (int T = 0; T < 2; ++T)
#pragma unroll
          for (int rg = 0; rg < 16; ++rg) {
            const int kv = kv0 + T * 32 + (rg & 3) + 8 * (rg >> 2) + 4 * hi;
            float v = sacc[T][rg];
            v = (kv <= qq) ? v : -1e30f;
            sacc[T][rg] = v;
            pmax = fmaxf(pmax, v);
          }
      } else {
#pragma unroll
        for (int T = 0; T < 2; ++T)
#pragma unroll
          for (int rg = 0; rg < 16; ++rg) pmax = fmaxf(pmax, sacc[T][rg]);
      }
      pmax = fmaxf(pmax, __shfl_xor(pmax, 32, 64));

      const float corr = __expf(mrow - pmax);
      mrow = pmax;
      float lsum = 0.f;
#pragma unroll
      for (int T = 0; T < 2; ++T)
#pragma unroll
        for (int rg = 0; rg < 16; ++rg) {
          const float p = __expf(sacc[T][rg] - mrow);
          sacc[T][rg] = p;
          lsum += p;
        }
      lsum += __shfl_xor(lsum, 32, 64);
      lrow = lrow * corr + lsum;
#pragma unroll
      for (int tt = 0; tt < 2; ++tt)
#pragma unroll
        for (int rg = 0; rg < 16; ++rg) oacc[tt][rg] *= corr;

      // P^T in-register (cvt_pk + permlane32_swap), then O^T += V^T P^T
      __builtin_amdgcn_s_setprio(1);
#pragma unroll
      for (int T = 0; T < 2; ++T)
#pragma unroll
        for (int c = 0; c < 2; ++c) {
          unsigned int x0 = pkbf(sacc[T][8 * c + 0], sacc[T][8 * c + 1]);
          unsigned int x1 = pkbf(sacc[T][8 * c + 2], sacc[T][8 * c + 3]);
          unsigned int x2 = pkbf(sacc[T][8 * c + 4], sacc[T][8 * c + 5]);
          unsigned int x3 = pkbf(sacc[T][8 * c + 6], sacc[T][8 * c + 7]);
          plswap(x0, x2);   // -> word0, word2
          plswap(x1, x3);   // -> word1, word3
          union { unsigned int u[4]; bf16x8 v; } pb;
          pb.u[0] = x0; pb.u[1] = x1; pb.u[2] = x2; pb.u[3] = x3;
#pragma unroll
          for (int tt = 0; tt < 2; ++tt) {
            const int hd = tt * 32 + l31;
            const int slot = (T * 4 + c * 2 + hi) ^ (hd & 7);
            bf16x8 vf = *(const bf16x8*)(&ldsV[cur][hd * 64 + slot * 8]);
            oacc[tt] = __builtin_amdgcn_mfma_f32_32x32x16_bf16(vf, pb.v, oacc[tt], 0, 0, 0);
          }
        }
      __builtin_amdgcn_s_setprio(0);
    }

    asm volatile("s_waitcnt vmcnt(0)" ::: "memory");
    __syncthreads();
  }

  // epilogue: y[q][hd] = O^T[hd][q] / l   (bf16)
  const float inv = 1.f / lrow;
  unsigned short* yp = y + (size_t)(b * S_ + qq) * D_ + h * HD_;
#pragma unroll
  for (int tt = 0; tt < 2; ++tt)
#pragma unroll
    for (int rg = 0; rg < 16; rg += 2) {
      unsigned int pk = pkbf(oacc[tt][rg] * inv, oacc[tt][rg + 1] * inv);
      const int hd = tt * 32 + (rg & 3) + 8 * (rg >> 2) + 4 * hi;
      *(unsigned int*)(yp + hd) = pk;
    }
}

// ---------------- launch ----------------
extern "C" void kernel_launch(void* const* d_in, const int* in_sizes, int n_in,
                              void* d_out, int out_size, void* d_ws, size_t ws_size,
                              hipStream_t stream) {
  const float* x  = (const float*)d_in[0];   // [2,2048,1024]
  const float* wa = (const float*)d_in[1];   // [1024,3072]
  const float* wp = (const float*)d_in[2];   // [1024,1024]
  float* out = (float*)d_out;                // [2,2048,1024] fp32

  char* ws = (char*)d_ws;
  // ws layout (bytes), all 256B-aligned; total = 56 MiB
  unsigned short* xb  = (unsigned short*)(ws + 0);          //  8 MiB: x bf16 [4096][1024]
  unsigned short* waT = (unsigned short*)(ws + 8388608);    //  6 MiB: w_attn^T [3072][1024]
  unsigned short* wpT = (unsigned short*)(ws + 14680064);   //  2 MiB: w_proj^T [1024][1024]
  unsigned short* qkv = (unsigned short*)(ws + 16777216);   // 24 MiB: [4096][3072]
  unsigned short* vtb = (unsigned short*)(ws + 41943040);   //  8 MiB: [32][64][2048]
  unsigned short* yb  = (unsigned short*)(ws + 50331648);   //  8 MiB: [4096][1024]

  k_convert_x<<<4096, 256, 0, stream>>>(x, xb);
  k_transpose_w<<<dim3(48, 16), 256, 0, stream>>>(wa, waT, D_, TD_);
  k_transpose_w<<<dim3(16, 16), 256, 0, stream>>>(wp, wpT, D_, D_);
  k_gemm_bt<1><<<dim3(24, 32), 256, 0, stream>>>(xb, waT, qkv, TD_, D_);
  k_transpose_v<<<dim3(32, 32), 256, 0, stream>>>(qkv, vtb);
  k_attn<<<512, 256, 0, stream>>>(qkv, vtb, yb);
  k_gemm_bt<0><<<dim3(8, 32), 256, 0, stream>>>(yb, wpT, out, D_, D_);
}